// Round 3
// baseline (150.568 us; speedup 1.0000x reference)
//
#include <hip/hip_runtime.h>
#include <math.h>

#define K_TOP 512
#define CAND_CAP 3072

struct LvlC {
  int H, lgH, HH, lgHH;
  float fs, wsc, hsc, wex, hex, pwlo, pwhi, phlo, phhi, minwh, maxwh;
};

__device__ const LvlC LVL[4] = {
  {128, 7, 16384, 14, 0.25f,    0.8f, 1.0f, 0.2f, 0.4f, 0.008f, 0.054f, 0.008f, 0.072f, 0.005f, 0.12f},
  { 64, 6,  4096, 12, 0.125f,   0.9f, 1.2f, 0.3f, 0.6f, 0.016f, 0.072f, 0.016f, 0.096f, 0.01f,  0.16f},
  { 32, 5,  1024, 10, 0.0625f,  1.0f, 1.4f, 0.4f, 0.8f, 0.024f, 0.09f,  0.024f, 0.12f,  0.015f, 0.2f },
  { 16, 4,   256,  8, 0.03125f, 1.1f, 1.6f, 0.5f, 1.0f, 0.032f, 0.108f, 0.032f, 0.144f, 0.02f,  0.24f},
};

// fixed candidate thresholds on sort_key (score in (0,1), invalid = -1).
// expected counts/segment: ~1510 / ~1460 / ~1870 / 768 — 26+ sigma inside [512, 3072].
// master falls back to exact full-N radix if a count ever lands outside.
__device__ const float TSEL[4] = {0.91f, 0.85f, 0.65f, -2.0f};

// rimg = 1/image_size, image_size = 512 = 2^9: multiply by exact 2^-9 == divide (IEEE exact).
__device__ __forceinline__ void decode_box(const LvlC& L, const float* __restrict__ boxp,
                                           const float* __restrict__ ancp,
                                           int b, int idx, float rimg,
                                           float& x0, float& y0, float& x1, float& y1)
{
#pragma clang fp contract(off)
  int a   = idx >> L.lgHH;
  int rem = idx & (L.HH - 1);
  const float* bp = boxp + (size_t)((b * 3 + a) * 4) * L.HH + rem;
  float d0 = bp[0], d1 = bp[L.HH], d2 = bp[2 * L.HH], d3 = bp[3 * L.HH];
  float4 av = reinterpret_cast<const float4*>(ancp)[idx];
  float a0 = av.x, a1 = av.y, a2 = av.z, a3 = av.w;
  float aw  = (a2 - a0) * rimg;
  float ah  = (a3 - a1) * rimg;
  float acx = (a0 + a2) * 0.5f * rimg;
  float acy = (a1 + a3) * 0.5f * rimg;
  float dx = fminf(fmaxf(d0 * 0.2f, -1.f), 1.f) * L.fs * aw;
  float dy = fminf(fmaxf(d1 * 0.2f, -1.f), 1.f) * L.fs * ah;
  float cx = fminf(fmaxf(acx + dx, 0.f), 1.f);
  float cy = fminf(fmaxf(acy + dy, 0.f), 1.f);
  float dw = fminf(fmaxf(d2 * 0.2f, -2.f), 2.f);
  float dh = fminf(fmaxf(d3 * 0.2f, -2.f), 2.f);
  float pw = fminf(fmaxf(aw * L.wsc * expf(dw * L.wex), L.pwlo), L.pwhi);
  float ph = fminf(fmaxf(ah * L.hsc * expf(dh * L.hex), L.phlo), L.phhi);
  x0 = fminf(fmaxf(cx - 0.5f * pw, 0.f), 1.f);
  y0 = fminf(fmaxf(cy - 0.5f * ph, 0.f), 1.f);
  x1 = fminf(fmaxf(cx + 0.5f * pw, 0.f), 1.f);
  y1 = fminf(fmaxf(cy + 0.5f * ph, 0.f), 1.f);
}

__device__ __forceinline__ void seg_map(int blk, int& b, int& l, int& base, int& iblk)
{
  b = blk / 255;                 // 255 units per batch (65280/256)
  int rb = blk - b * 255;
  if (rb < 192)      { l = 0; iblk = rb;       base = 0;     }
  else if (rb < 240) { l = 1; iblk = rb - 192; base = 49152; }
  else if (rb < 252) { l = 2; iblk = rb - 240; base = 61440; }
  else               { l = 3; iblk = rb - 252; base = 64512; }
}

// ========== Kernel 1: decode all anchors -> keys; threshold-compact candidates ==========
// Block 0 also zeroes the inter-block sync flags for kernel 2 (kernel boundary publishes).
__global__ __launch_bounds__(256) void dc_kernel(
    const float* __restrict__ cls0, const float* __restrict__ box0, const float* __restrict__ anc0,
    const float* __restrict__ cls1, const float* __restrict__ box1, const float* __restrict__ anc1,
    const float* __restrict__ cls2, const float* __restrict__ box2, const float* __restrict__ anc2,
    const float* __restrict__ cls3, const float* __restrict__ box3, const float* __restrict__ anc3,
    const int* __restrict__ imgp, unsigned long long* __restrict__ keys,
    unsigned long long* __restrict__ cand, unsigned* __restrict__ unitCnt,
    unsigned* __restrict__ flags)
{
  __shared__ unsigned wcnt[4];
  int unit = (int)blockIdx.x;
  int tid = (int)threadIdx.x;
  int wid = tid >> 6, lane = tid & 63;
  if (unit == 0 && tid < 64) flags[tid] = 0u;   // selDone[16] @0, maskDone[16] @16
  int b, l, base, iblk;
  seg_map(unit, b, l, base, iblk);
  int i = iblk * 256 + tid;

  const float *cls, *boxp, *ancp;
  switch (l) {
    case 0:  cls = cls0; boxp = box0; ancp = anc0; break;
    case 1:  cls = cls1; boxp = box1; ancp = anc1; break;
    case 2:  cls = cls2; boxp = box2; ancp = anc2; break;
    default: cls = cls3; boxp = box3; ancp = anc3; break;
  }
  LvlC L = LVL[l];
  float rimg = 1.0f / (float)(*imgp);

  int a   = i >> L.lgHH;
  int rem = i & (L.HH - 1);
  const float* cp = cls + (size_t)((b * 3 + a) * 3) * L.HH + rem;
  float c0 = cp[0], c1 = cp[L.HH], c2 = cp[2 * L.HH];
  float m = c0; int mc = 0;
  if (c1 > m) { m = c1; mc = 1; }
  if (c2 > m) { m = c2; mc = 2; }
  float ms = 1.f / (1.f + expf(-m));   // max of sigmoids == sigmoid of max logit

  float x0, y0, x1, y1;
  decode_box(L, boxp, ancp, b, i, rimg, x0, y0, x1, y1);
  float w = x1 - x0, h = y1 - y0;
  bool valid = (ms > 0.15f) && (w > L.minwh) && (h > L.minwh) && (w < L.maxwh) && (h < L.maxwh);

  float sk = valid ? ms : -1.0f;
  unsigned u = __float_as_uint(sk);
  unsigned ascu  = (u & 0x80000000u) ? ~u : (u | 0x80000000u);
  unsigned descu = ~ascu;
  unsigned long long key = ((unsigned long long)descu << 32)
                         | ((unsigned long long)(unsigned)i << 16)
                         | ((unsigned)mc << 8) | (valid ? 1u : 0u);
  keys[(size_t)b * 65280 + base + i] = key;

  bool take = (sk >= TSEL[l]);
  unsigned long long bm = __ballot(take);
  if (lane == 0) wcnt[wid] = (unsigned)__popcll(bm);
  __syncthreads();
  if (take) {
    unsigned off = 0;
    for (int w2 = 0; w2 < wid; ++w2) off += wcnt[w2];
    off += (unsigned)__popcll(bm & ((1ull << lane) - 1ull));
    cand[(size_t)unit * 256 + off] = key;
  }
  if (tid == 0) unitCnt[unit] = wcnt[0] + wcnt[1] + wcnt[2] + wcnt[3];
}

// ========== Kernel 2: FUSED pipeline — 16 master blocks (sel -> wait -> NMS -> out)
//                       + 256 mask blocks (16/segment), flag-synchronized ==========
// Deadlock-free: 272 blocks x 512thr, ~41.5KB LDS -> >=2 blocks/CU -> >=512 resident
// slots on 256 CUs => all blocks co-resident; producers have lowest block IDs anyway.
// Visibility: producers do __syncthreads (drains vmcnt) then agent-scope RELEASE add;
// consumers spin with agent-scope ACQUIRE load in thread 0, then __syncthreads.
__global__ __launch_bounds__(512) void post_kernel(
    const unsigned long long* __restrict__ keys,
    const unsigned long long* __restrict__ cand, const unsigned* __restrict__ unitCnt,
    const float* __restrict__ box0, const float* __restrict__ anc0,
    const float* __restrict__ box1, const float* __restrict__ anc1,
    const float* __restrict__ box2, const float* __restrict__ anc2,
    const float* __restrict__ box3, const float* __restrict__ anc3,
    const int* __restrict__ imgp,
    float* __restrict__ boxesWS, unsigned long long* __restrict__ masks,
    unsigned* __restrict__ flags, float* __restrict__ out)
{
  // LDS alias plan (master): sel uses scand[3072]u64 @0 | skey @24K | skey2 @28K | hist @32K.
  // scan phase reuses [0,32K) as sMaskT[8*512]u64 (all sel reads done before overwrite).
  __shared__ alignas(16) char smem[40960];
  unsigned long long* scand  = (unsigned long long*)(smem);
  unsigned long long* skey   = (unsigned long long*)(smem + 24576);
  unsigned long long* skey2  = (unsigned long long*)(smem + 28672);
  unsigned (*hist)[256]      = (unsigned (*)[256])(smem + 32768);
  unsigned long long* sMaskT = (unsigned long long*)(smem);
  __shared__ unsigned upref[256];
  __shared__ unsigned waveSum[8];
  __shared__ unsigned long long keepW[2][8];
  __shared__ unsigned cfl[2];
  __shared__ unsigned long long shPrefix;
  __shared__ unsigned long long shKth;
  __shared__ unsigned shBelow, shCnt, shTotal, shBucketCnt, sBC;

  int tid = (int)threadIdx.x;
  int wid = tid >> 6, lane = tid & 63;
  const int nt = 512;

  // =================== MASK ROLE (blocks 16..271) ===================
  if (blockIdx.x >= 16) {
#pragma clang fp contract(off)
    int m = (int)blockIdx.x - 16;
    int seg = m >> 4, sub = m & 15;
    if (tid == 0) {
      int guard = 0;
      while (__hip_atomic_load(&flags[seg], __ATOMIC_ACQUIRE, __HIP_MEMORY_SCOPE_AGENT) == 0u) {
        __builtin_amdgcn_s_sleep(2);
        if (++guard > 4000000) break;   // safety: proceed (would show as absmax fail)
      }
    }
    __syncthreads();
    const float4* bb = reinterpret_cast<const float4*>(boxesWS) + seg * K_TOP;
    unsigned long long* mseg = masks + (size_t)seg * K_TOP * 8;
    int waveInSeg = sub * 8 + wid;          // 0..127, 4 rows each
    float4 bj[8]; float aj[8];
#pragma unroll
    for (int c = 0; c < 8; ++c) {
      bj[c] = bb[c * 64 + lane];
      aj[c] = (bj[c].z - bj[c].x) * (bj[c].w - bj[c].y);
    }
#pragma unroll
    for (int rr = 0; rr < 4; ++rr) {
      int r = waveInSeg * 4 + rr;
      float4 br = bb[r];
      float ar_ = (br.z - br.x) * (br.w - br.y);
#pragma unroll
      for (int c = 0; c < 8; ++c) {
        float ltx = fmaxf(br.x, bj[c].x), lty = fmaxf(br.y, bj[c].y);
        float rbx = fminf(br.z, bj[c].z), rby = fminf(br.w, bj[c].w);
        float ww = fmaxf(rbx - ltx, 0.f), hh = fmaxf(rby - lty, 0.f);
        float inter = ww * hh;
        float iou = inter / (ar_ + aj[c] - inter + 1e-9f);
        unsigned long long bal = __ballot(iou > 0.5f);
        if (lane == 0) mseg[c * K_TOP + r] = bal;   // transposed: [word][row]
      }
    }
    __syncthreads();   // drain all waves' mask stores (vmcnt(0) per wave before barrier)
    if (tid == 0)
      __hip_atomic_fetch_add(&flags[16 + seg], 1u, __ATOMIC_RELEASE, __HIP_MEMORY_SCOPE_AGENT);
    return;
  }

  // =================== MASTER ROLE (blocks 0..15) ===================
  int seg = (int)blockIdx.x;
  int b = seg >> 2, l = seg & 3;

  const int nArr[4]    = {49152, 12288, 3072, 768};
  const int baseArr[4] = {0, 49152, 61440, 64512};
  const int nuArr[4]   = {192, 48, 12, 3};
  const int fuArr[4]   = {0, 192, 240, 252};
  int N = nArr[l];
  int nu = nuArr[l];
  int firstU = b * 255 + fuArr[l];
  const unsigned long long* kp = keys + (size_t)b * 65280 + baseArr[l];

  if (tid == 0) { shPrefix = 0ull; shBelow = 0u; shCnt = 0u; sBC = 0u; shBucketCnt = 0xFFFFFFFFu; }

  // ---- per-unit counts; prefix-scan ----
  unsigned c = (tid < nu) ? unitCnt[firstU + tid] : 0u;
  unsigned incl = c;
  for (int off = 1; off < 64; off <<= 1) {
    unsigned n = __shfl_up(incl, off);
    if (lane >= off) incl += n;
  }
  if (lane == 63) waveSum[wid] = incl;
  __syncthreads();
  if (tid < 256) {
    unsigned add = 0;
    for (int w2 = 0; w2 < wid; ++w2) add += waveSum[w2];
    if (tid < nu) upref[tid] = incl - c + add;
  }
  if (tid == 0) shTotal = waveSum[0] + waveSum[1] + waveSum[2] + waveSum[3];
  __syncthreads();

  unsigned total = shTotal;
  bool useCand = (total >= K_TOP && total <= CAND_CAP);
  int M = useCand ? (int)total : N;

  // ---- gather candidates to LDS ----
  if (useCand) {
    for (int f = tid; f < (int)total; f += nt) {
      int lo = 0, hi = nu - 1;
      while (lo < hi) {
        int mid = (lo + hi + 1) >> 1;
        if ((int)upref[mid] <= f) lo = mid; else hi = mid - 1;
      }
      scand[f] = cand[(size_t)(firstU + lo) * 256 + (unsigned)(f - (int)upref[lo])];
    }
  }
  __syncthreads();

  // ---- radix select with early exit (bits 63..16; keys unique in those bits) ----
  int lastShift = 16;
  for (int r = 0; r < 6; ++r) {
    int shift = 56 - 8 * r;
    for (int v = tid; v < 8 * 256; v += nt) ((unsigned*)hist)[v] = 0u;
    __syncthreads();
    unsigned long long pref = shPrefix;
    unsigned below = shBelow;
    unsigned long long hiMask = (r == 0) ? 0ull : (~0ull << (64 - 8 * r));
    for (int t = tid; t < M; t += nt) {
      unsigned long long k = useCand ? scand[t] : kp[t];
      if ((k & hiMask) == (pref & hiMask))
        atomicAdd(&hist[wid][(unsigned)((k >> shift) & 0xFF)], 1u);
    }
    __syncthreads();
    unsigned s = 0, incl2 = 0;
    if (tid < 256) {
#pragma unroll
      for (int w2 = 0; w2 < 8; ++w2) s += hist[w2][tid];
      incl2 = s;
    }
    for (int off = 1; off < 64; off <<= 1) {
      unsigned n = __shfl_up(incl2, off);
      if (lane >= off) incl2 += n;
    }
    if (lane == 63) waveSum[wid] = incl2;
    __syncthreads();
    if (tid < 256) {
      unsigned add = 0;
      for (int w2 = 0; w2 < wid; ++w2) add += waveSum[w2];
      unsigned inclT = incl2 + add;
      unsigned exclT = inclT - s;
      if (below + exclT < K_TOP && below + inclT >= K_TOP) {
        shBelow = below + exclT;
        shPrefix = pref | ((unsigned long long)(unsigned)tid << shift);
        shBucketCnt = s;                 // boundary-bucket population
      }
    }
    __syncthreads();
    if (shBucketCnt <= (unsigned)K_TOP) { lastShift = shift; break; }  // uniform
  }

  // ---- exact kth: collect boundary bucket (<=512), rank with full-key compares ----
  {
    unsigned long long pmask = ~0ull << lastShift;
    unsigned long long pref = shPrefix;
    for (int t = tid; t < M; t += nt) {
      unsigned long long k = useCand ? scand[t] : kp[t];
      bool take = ((k & pmask) == pref);
      unsigned long long bm = __ballot(take);
      unsigned bp = 0;
      if (lane == 0 && bm) bp = atomicAdd(&sBC, (unsigned)__popcll(bm));
      bp = __shfl(bp, 0);
      if (take) skey[bp + (unsigned)__popcll(bm & ((1ull << lane) - 1ull))] = k;
    }
    __syncthreads();
    unsigned cnt = sBC;
    unsigned rneed = K_TOP - shBelow;      // in [1, cnt]
    if (tid < (int)cnt) {
      unsigned long long mykey = skey[tid];
      int rank = 0;
      for (unsigned j = 0; j < cnt; ++j) rank += (skey[j] < mykey) ? 1 : 0;
      if (rank == (int)(rneed - 1)) shKth = mykey;
    }
    __syncthreads();
  }
  unsigned long long kth = shKth;

  // ---- collect exactly 512 keys <= kth ----
  for (int t = tid; t < M; t += nt) {
    unsigned long long k = useCand ? scand[t] : kp[t];
    bool take = (k <= kth);
    unsigned long long bm = __ballot(take);
    unsigned bp = 0;
    if (lane == 0 && bm) bp = atomicAdd(&shCnt, (unsigned)__popcll(bm));
    bp = __shfl(bp, 0);
    if (take) skey[bp + (unsigned)__popcll(bm & ((1ull << lane) - 1ull))] = k;
  }
  __syncthreads();

  // ---- rank-scatter into sorted order (keys unique) ----
  {
    unsigned long long mykey = skey[tid];
    int rank = 0;
#pragma unroll 8
    for (int j = 0; j < K_TOP; ++j) rank += (skey[j] < mykey) ? 1 : 0;
    skey2[rank] = mykey;
  }
  __syncthreads();

  // ---- decode my selected box; keep everything in registers ----
  const float *boxp, *ancp;
  switch (l) {
    case 0:  boxp = box0; ancp = anc0; break;
    case 1:  boxp = box1; ancp = anc1; break;
    case 2:  boxp = box2; ancp = anc2; break;
    default: boxp = box3; ancp = anc3; break;
  }
  LvlC L = LVL[l];
  float rimg = 1.0f / (float)(*imgp);

  unsigned long long key = skey2[tid];
  int idx = (int)((key >> 16) & 0xFFFFull);
  unsigned descu = (unsigned)(key >> 32);
  unsigned ascu  = ~descu;
  unsigned u = (ascu & 0x80000000u) ? (ascu & 0x7FFFFFFFu) : ~ascu;
  int label = (int)((key >> 8) & 0xFFull);
  bool valid = (key & 1ull) != 0ull;
  float x0, y0, x1, y1;
  decode_box(L, boxp, ancp, b, idx, rimg, x0, y0, x1, y1);
  float4 mybox; mybox.x = x0; mybox.y = y0; mybox.z = x1; mybox.w = y1;
  reinterpret_cast<float4*>(boxesWS)[seg * K_TOP + tid] = mybox;
  __syncthreads();   // all boxesWS stores drained (vmcnt(0) per wave); skey2 reads done

  // ---- signal sel done; wait for this segment's 16 mask blocks ----
  if (tid == 0) {
    __hip_atomic_fetch_add(&flags[seg], 1u, __ATOMIC_RELEASE, __HIP_MEMORY_SCOPE_AGENT);
    int guard = 0;
    while (__hip_atomic_load(&flags[16 + seg], __ATOMIC_ACQUIRE, __HIP_MEMORY_SCOPE_AGENT) < 16u) {
      __builtin_amdgcn_s_sleep(2);
      if (++guard > 4000000) break;
    }
  }
  __syncthreads();

  // ---- load masks (LDS alias over dead sel scratch), Jacobi-fixpoint greedy NMS ----
  const unsigned long long* mp = masks + (size_t)seg * K_TOP * 8;
#pragma unroll
  for (int w = 0; w < 8; ++w) sMaskT[w * K_TOP + tid] = mp[w * K_TOP + tid];  // own slots
  unsigned long long myWord = __ballot(valid);
  if (lane == 0) keepW[0][wid] = myWord;
  __syncthreads();

  int p = 0;
  for (int it = 0; it < 600; ++it) {
    unsigned long long kws[8];
#pragma unroll
    for (int w = 0; w < 8; ++w) kws[w] = keepW[p][w];
    unsigned long long sup = 0ull;
    for (int w = 0; w < wid; ++w)
      sup |= sMaskT[w * K_TOP + tid] & kws[w];
    sup |= sMaskT[wid * K_TOP + tid] & kws[wid] & ((1ull << lane) - 1ull);
    bool nk = valid && (sup == 0ull);
    unsigned long long nw = __ballot(nk);
    if (tid == 0) cfl[p ^ 1] = 0u;
    __syncthreads();                      // reads of keepW[p] done; cfl[p^1] zeroed
    if (lane == 0) {
      keepW[p ^ 1][wid] = nw;
      if (nw != kws[wid]) atomicOr(&cfl[p ^ 1], 1u);
    }
    __syncthreads();
    if (cfl[p ^ 1] == 0u) break;
    p ^= 1;
  }
  int pf = p ^ 1;                          // newest keep state

  // ---- outputs (all from registers) ----
  int o = seg * K_TOP + tid;
  bool keep = (keepW[pf][wid] >> lane) & 1ull;
  float4 ob;
  ob.x = keep ? mybox.x : 0.f;
  ob.y = keep ? mybox.y : 0.f;
  ob.z = keep ? mybox.z : 0.f;
  ob.w = keep ? mybox.w : 0.f;
  reinterpret_cast<float4*>(out)[o] = ob;                   // boxes:  [0,      32768)
  out[32768 + o] = keep ? __uint_as_float(u) : 0.f;         // scores: [32768,  40960)
  out[40960 + o] = keep ? (float)(label + 1) : 0.f;         // labels: [40960,  49152)
  out[49152 + o] = keep ? 1.f : 0.f;                        // keep:   [49152,  57344)
}

extern "C" void kernel_launch(void* const* d_in, const int* in_sizes, int n_in,
                              void* d_out, int out_size, void* d_ws, size_t ws_size,
                              hipStream_t stream)
{
  const float* cls0 = (const float*)d_in[0];
  const float* box0 = (const float*)d_in[1];
  const float* anc0 = (const float*)d_in[2];
  const float* cls1 = (const float*)d_in[3];
  const float* box1 = (const float*)d_in[4];
  const float* anc1 = (const float*)d_in[5];
  const float* cls2 = (const float*)d_in[6];
  const float* box2 = (const float*)d_in[7];
  const float* anc2 = (const float*)d_in[8];
  const float* cls3 = (const float*)d_in[9];
  const float* box3 = (const float*)d_in[10];
  const float* anc3 = (const float*)d_in[11];
  const int*   imgp = (const int*)d_in[12];

  // ws layout (bytes) — flags zeroed by dc block 0 each iteration:
  char* ws = (char*)d_ws;
  unsigned long long* keys    = (unsigned long long*)(ws + 0);         // 2,088,960
  unsigned long long* cand    = (unsigned long long*)(ws + 2088960);   // 2,088,960
  unsigned*           unitCnt = (unsigned*)(ws + 4177920);             // 4,096
  float*              boxesWS = (float*)(ws + 4182016);                // 131,072
  unsigned long long* masks   = (unsigned long long*)(ws + 4313088);   // 524,288
  unsigned*           flags   = (unsigned*)(ws + 4837376);             // 256
  float* out = (float*)d_out;

  dc_kernel<<<1020, 256, 0, stream>>>(cls0, box0, anc0, cls1, box1, anc1,
                                      cls2, box2, anc2, cls3, box3, anc3,
                                      imgp, keys, cand, unitCnt, flags);
  post_kernel<<<272, 512, 0, stream>>>(keys, cand, unitCnt,
                                       box0, anc0, box1, anc1, box2, anc2, box3, anc3,
                                       imgp, boxesWS, masks, flags, out);
}